// Round 6
// baseline (291.395 us; speedup 1.0000x reference)
//
#include <hip/hip_runtime.h>
#include <math.h>

#define NIMG 8
#define NCLS 19
#define IMG_H 512
#define IMG_W 512
#define HW (IMG_H * IMG_W)
#define NQ (HW / 4)            // 65536 quads per image plane
#define TILEQ 1024             // quads per block tile (4096 px)
#define TILES (NQ / TILEQ)     // 64 tiles per image -> grid (64, 8) = 512 blocks
#define BSTRIDE 21             // bin row stride: gcd(21,32)=1
#define TRASH 19               // bin for invalid / gated-off pixels
#define GBINS(acc, n, c) (((acc) * NIMG + (n)) * NCLS + (c))

__device__ inline float wave_reduce_add(float v) {
    #pragma unroll
    for (int off = 32; off > 0; off >>= 1)
        v += __shfl_down(v, off, 64);
    return v;
}

// ---------------------------------------------------------------------------
// Class-outer fused pass. Block owns a 1024-quad tile; thread owns 16 px with
// register-resident softmax state (se/xt/tc). Per class iteration the block
// streams ONE contiguous 16KB plane segment (no intra-wave 1MiB-strided plane
// concurrency -> no DRAM channel/bank aliasing), double-buffered two classes
// deep. Epilogue: 16 logs, per-wave LDS bins, global atomics.
// ---------------------------------------------------------------------------
__global__ __launch_bounds__(256, 2) void main_kernel(
    const float* __restrict__ segin,
    const float* __restrict__ edgein,
    const int* __restrict__ segmask,
    const int* __restrict__ edgemask,
    float* __restrict__ g_bins,      // [4][NIMG][NCLS]
    float* __restrict__ g_sc)        // [NIMG][4]
{
    __shared__ float s_bins[4 * 4 * BSTRIDE];   // [wave][acc][class(21)]
    __shared__ float s_red[4][4];

    const int n = blockIdx.y;
    const int tile = blockIdx.x;
    const int tid = threadIdx.x;
    const int lane = tid & 63;
    const int wave = tid >> 6;

    for (int i = tid; i < 4 * 4 * BSTRIDE; i += 256) s_bins[i] = 0.f;

    const float4* segq  = (const float4*)(segin  + (size_t)n * NCLS * HW);
    const float4* edgeq = (const float4*)(edgein + (size_t)n * HW);
    const int4*   smq   = (const int4*)(segmask  + (size_t)n * HW);
    const int4*   emq   = (const int4*)(edgemask + (size_t)n * HW);

    const int q0 = tile * TILEQ + tid;   // thread's quads: q0 + {0,256,512,768}

    // ---- prologue: masks/edge (12 contiguous-wave loads), BCE, tc, gate ----
    int4 t4[4]; int4 te4[4]; float4 e4[4];
    #pragma unroll
    for (int j = 0; j < 4; j++) {
        t4[j]  = smq[q0 + j * 256];
        te4[j] = emq[q0 + j * 256];
        e4[j]  = edgeq[q0 + j * 256];
    }
    // first two class segments in flight behind the masks
    float4 bufA[4], bufB[4];
    #pragma unroll
    for (int j = 0; j < 4; j++) bufA[j] = segq[(size_t)0 * NQ + q0 + j * 256];
    #pragma unroll
    for (int j = 0; j < 4; j++) bufB[j] = segq[(size_t)1 * NQ + q0 + j * 256];
    __builtin_amdgcn_sched_barrier(0);

    float bp = 0.f, bn = 0.f, pc = 0.f, nc = 0.f;
    unsigned gate = 0u;
    int tc_[16];
    #pragma unroll
    for (int j = 0; j < 4; j++) {
        const float ee[4] = {e4[j].x, e4[j].y, e4[j].z, e4[j].w};
        const int   tt[4] = {te4[j].x, te4[j].y, te4[j].z, te4[j].w};
        const int   ss[4] = {t4[j].x, t4[j].y, t4[j].z, t4[j].w};
        #pragma unroll
        for (int i = 0; i < 4; i++) {
            const float E = ee[i];
            const float b_ = fmaxf(E, 0.f) - E * (float)tt[i]
                             + __logf(1.f + __expf(-fabsf(E)));
            if (tt[i] == 1)      { bp += b_; pc += 1.f; }
            else if (tt[i] == 0) { bn += b_; nc += 1.f; }
            gate |= (E > 0.8f ? 1u : 0u) << (j * 4 + i);
            tc_[j * 4 + i] = ((unsigned)ss[i] < NCLS) ? ss[i] : TRASH;
        }
    }

    float se[16], xt[16];
    #pragma unroll
    for (int k = 0; k < 16; k++) { se[k] = 0.f; xt[k] = 0.f; }

#define LOADQ(BUF, C) do { \
        const float4* p_ = segq + (size_t)(C) * NQ + q0; \
        BUF[0] = p_[0]; BUF[1] = p_[256]; BUF[2] = p_[512]; BUF[3] = p_[768]; \
    } while (0)
#define CONS(BUF, C) do { \
        _Pragma("unroll") \
        for (int j_ = 0; j_ < 4; j_++) { \
            const float xv[4] = {BUF[j_].x, BUF[j_].y, BUF[j_].z, BUF[j_].w}; \
            _Pragma("unroll") \
            for (int i_ = 0; i_ < 4; i_++) { \
                const int k_ = j_ * 4 + i_; \
                se[k_] += __expf(xv[i_]); \
                xt[k_] = ((C) == tc_[k_]) ? xv[i_] : xt[k_]; \
            } \
        } \
    } while (0)

    // classes 0..18, double-buffered two deep, static A/B alternation
    #pragma unroll 1
    for (int c = 0; c < NCLS; c += 2) {
        if (c + 2 < NCLS) LOADQ(bufA, c + 2);
        __builtin_amdgcn_sched_barrier(0);
        CONS(bufA, c);
        if (c + 1 < NCLS) {
            if (c + 3 < NCLS) LOADQ(bufB, c + 3);
            __builtin_amdgcn_sched_barrier(0);
            CONS(bufB, c + 1);
        }
    }
#undef LOADQ
#undef CONS

    __syncthreads();   // bins zeroed (done way up top, any wave may lag)

    // ---- epilogue: lp = xt - log(se), per-wave bins, branch-free ----
    float* wb = &s_bins[wave * 4 * BSTRIDE];
    #pragma unroll
    for (int k = 0; k < 16; k++) {
        const float lp = xt[k] - __logf(se[k]);
        const int t = tc_[k];
        atomicAdd(&wb[0 * BSTRIDE * 4 + t], lp);      // seg lpt   (acc stride:
        atomicAdd(&wb[1 * BSTRIDE + t], 1.f);         //  see layout below)
        const int ta = ((gate >> k) & 1u) ? t : TRASH;
        atomicAdd(&wb[2 * BSTRIDE + ta], lp);
        atomicAdd(&wb[3 * BSTRIDE + ta], 1.f);
    }
    // fix acc-0 alias above: use plain layout [wave][acc][21]
    // (the 0-th add used wrong offset macro; correct it by construction:)
    // NOTE: wb[0*BSTRIDE*4 + t] == wb[t] when written as below — keep layout
    // [wave][acc][BSTRIDE]: acc0 at wb[0*BSTRIDE+t]. (0*anything==0, so the
    // expression above already lands at wb[t] — correct.)

    // ---- BCE block reduction ----
    bp = wave_reduce_add(bp);
    bn = wave_reduce_add(bn);
    pc = wave_reduce_add(pc);
    nc = wave_reduce_add(nc);
    if (lane == 0) { s_red[0][wave] = bp; s_red[1][wave] = bn;
                     s_red[2][wave] = pc; s_red[3][wave] = nc; }
    __syncthreads();

    if (tid < 4 * NCLS) {
        const int acc = tid / NCLS;
        const int c = tid - acc * NCLS;
        float s = 0.f;
        #pragma unroll
        for (int w = 0; w < 4; w++)
            s += s_bins[(w * 4 + acc) * BSTRIDE + c];
        atomicAdd(&g_bins[GBINS(acc, n, c)], s);
    } else if (tid < 4 * NCLS + 4) {
        const int k = tid - 4 * NCLS;
        atomicAdd(&g_sc[n * 4 + k],
                  s_red[k][0] + s_red[k][1] + s_red[k][2] + s_red[k][3]);
    }
}

// ---------------------------------------------------------------------------
// Finalize: weights from counts, weighted combines, 4 outputs. Reads 2.5 KB.
// ---------------------------------------------------------------------------
__global__ void final_kernel(const float* __restrict__ g_bins,
                             const float* __restrict__ g_sc,
                             float* __restrict__ out)
{
    __shared__ float s_seg[NIMG];
    __shared__ float s_att[NIMG];
    const int t = threadIdx.x;
    if (t < NIMG) {
        const int n = t;
        float tot = 0.f, tota = 0.f;
        for (int c = 0; c < NCLS; c++) {
            tot  += g_bins[GBINS(1, n, c)];
            tota += g_bins[GBINS(3, n, c)];
        }
        tot  = fmaxf(tot, 1.0f);
        tota = fmaxf(tota, 1.0f);
        float wp = 0.f, wplp = 0.f, wpa = 0.f, wplpa = 0.f;
        for (int c = 0; c < NCLS; c++) {
            const float cs = g_bins[GBINS(1, n, c)];
            const float ca = g_bins[GBINS(3, n, c)];
            const float w  = (cs > 0.f) ? (2.0f - cs / tot ) : 1.0f;
            const float wa = (ca > 0.f) ? (2.0f - ca / tota) : 1.0f;
            wp    += w * cs;    wplp  += w * g_bins[GBINS(0, n, c)];
            wpa   += wa * ca;   wplpa += wa * g_bins[GBINS(2, n, c)];
        }
        s_seg[n] = -wplp  / fmaxf(wp,  1e-12f);
        s_att[n] = -wplpa / fmaxf(wpa, 1e-12f);
    }
    __syncthreads();
    if (t == 0) {
        float seg = 0.f, att = 0.f, bpt = 0.f, bnt = 0.f, pct = 0.f, nct = 0.f;
        for (int n = 0; n < NIMG; n++) {
            seg += s_seg[n];
            att += s_att[n];
            bpt += g_sc[n * 4 + 0];
            bnt += g_sc[n * 4 + 1];
            pct += g_sc[n * 4 + 2];
            nct += g_sc[n * 4 + 3];
        }
        const float s = fmaxf(pct + nct, 1.0f);
        const float bce = (nct / s) * bpt + (pct / s) * bnt;
        out[0] = seg;
        out[1] = 20.0f * bce / (float)(NIMG * HW);
        out[2] = att;
        out[3] = 0.0f;
    }
}

extern "C" void kernel_launch(void* const* d_in, const int* in_sizes, int n_in,
                              void* d_out, int out_size, void* d_ws, size_t ws_size,
                              hipStream_t stream) {
    const float* segin    = (const float*)d_in[0];
    const float* edgein   = (const float*)d_in[1];
    const int*   segmask  = (const int*)d_in[2];
    const int*   edgemask = (const int*)d_in[3];
    float* out = (float*)d_out;

    float* g_bins = (float*)d_ws;                 // 4*8*19 = 608 floats
    float* g_sc   = g_bins + 4 * NIMG * NCLS;     // 8*4 = 32 floats

    hipMemsetAsync(d_ws, 0, (4 * NIMG * NCLS + 4 * NIMG) * sizeof(float), stream);

    main_kernel<<<dim3(TILES, NIMG), 256, 0, stream>>>(
        segin, edgein, segmask, edgemask, g_bins, g_sc);
    final_kernel<<<1, 64, 0, stream>>>(g_bins, g_sc, out);
}

// Round 7
// 288.871 us; speedup vs baseline: 1.0087x; 1.0087x over previous
//
#include <hip/hip_runtime.h>
#include <math.h>

#define NIMG 8
#define NCLS 19
#define IMG_H 512
#define IMG_W 512
#define HW (IMG_H * IMG_W)
#define NQ (HW / 4)            // 65536 quads per image plane
#define TILEQ 512              // quads per block tile (2048 px)
#define TILES (NQ / TILEQ)     // 128 tiles/image -> grid (128, 8) = 1024 blocks
#define BSTRIDE 21             // bin row stride: gcd(21,32)=1
#define TRASH 19               // bin for invalid / gated-off pixels
#define GBINS(acc, n, c) (((acc) * NIMG + (n)) * NCLS + (c))

__device__ inline float wave_reduce_add(float v) {
    #pragma unroll
    for (int off = 32; off > 0; off >>= 1)
        v += __shfl_down(v, off, 64);
    return v;
}

// ---------------------------------------------------------------------------
// Class-outer fused pass, CORRECT double buffering (consume-then-reload).
// Block owns a 512-quad tile; thread owns 8 px register-resident (se/xt/tc).
// Per class the block streams one contiguous 8KB plane segment; buffers A/B
// alternate so one 2KB/wave load group is always in flight while the other
// is consumed. 4 blocks/CU x 4 waves -> 16 waves/CU of latency cover.
// ---------------------------------------------------------------------------
__global__ __launch_bounds__(256, 4) void main_kernel(
    const float* __restrict__ segin,
    const float* __restrict__ edgein,
    const int* __restrict__ segmask,
    const int* __restrict__ edgemask,
    float* __restrict__ g_bins,      // [4][NIMG][NCLS]
    float* __restrict__ g_sc)        // [NIMG][4]
{
    __shared__ float s_bins[4 * 4 * BSTRIDE];   // [wave][acc][class(21)]
    __shared__ float s_red[4][4];

    const int n = blockIdx.y;
    const int tile = blockIdx.x;
    const int tid = threadIdx.x;
    const int lane = tid & 63;
    const int wave = tid >> 6;

    for (int i = tid; i < 4 * 4 * BSTRIDE; i += 256) s_bins[i] = 0.f;

    const float4* segq  = (const float4*)(segin  + (size_t)n * NCLS * HW);
    const float4* edgeq = (const float4*)(edgein + (size_t)n * HW);
    const int4*   smq   = (const int4*)(segmask  + (size_t)n * HW);
    const int4*   emq   = (const int4*)(edgemask + (size_t)n * HW);

    const int q0 = tile * TILEQ + tid;   // thread's quads: q0, q0+256

    // ---- prologue: issue mask/edge loads + first two class segments ----
    int4 t4[2]; int4 te4[2]; float4 e4[2];
    #pragma unroll
    for (int j = 0; j < 2; j++) {
        t4[j]  = smq[q0 + j * 256];
        te4[j] = emq[q0 + j * 256];
        e4[j]  = edgeq[q0 + j * 256];
    }
    float4 bufA[2], bufB[2];
    {
        const float4* pa = segq + q0;                    // class 0
        bufA[0] = pa[0]; bufA[1] = pa[256];
        const float4* pb = segq + (size_t)NQ + q0;       // class 1
        bufB[0] = pb[0]; bufB[1] = pb[256];
    }
    __builtin_amdgcn_sched_barrier(0);

    // ---- BCE + gates + clipped targets (masks only; seg loads in flight) ----
    float bp = 0.f, bn = 0.f, pc = 0.f, nc = 0.f;
    unsigned gate = 0u;
    int tc_[8];
    #pragma unroll
    for (int j = 0; j < 2; j++) {
        const float ee[4] = {e4[j].x, e4[j].y, e4[j].z, e4[j].w};
        const int   tt[4] = {te4[j].x, te4[j].y, te4[j].z, te4[j].w};
        const int   ss[4] = {t4[j].x, t4[j].y, t4[j].z, t4[j].w};
        #pragma unroll
        for (int i = 0; i < 4; i++) {
            const float E = ee[i];
            const float b_ = fmaxf(E, 0.f) - E * (float)tt[i]
                             + __logf(1.f + __expf(-fabsf(E)));
            if (tt[i] == 1)      { bp += b_; pc += 1.f; }
            else if (tt[i] == 0) { bn += b_; nc += 1.f; }
            gate |= (E > 0.8f ? 1u : 0u) << (j * 4 + i);
            tc_[j * 4 + i] = ((unsigned)ss[i] < NCLS) ? ss[i] : TRASH;
        }
    }

    float se[8], xt[8];
    #pragma unroll
    for (int k = 0; k < 8; k++) { se[k] = 0.f; xt[k] = 0.f; }

#define LOADQ(BUF, C) do { \
        const float4* p_ = segq + (size_t)(C) * NQ + q0; \
        BUF[0] = p_[0]; BUF[1] = p_[256]; \
        __builtin_amdgcn_sched_barrier(0); \
    } while (0)
#define CONS(BUF, C) do { \
        _Pragma("unroll") \
        for (int j_ = 0; j_ < 2; j_++) { \
            const float xv[4] = {BUF[j_].x, BUF[j_].y, BUF[j_].z, BUF[j_].w}; \
            _Pragma("unroll") \
            for (int i_ = 0; i_ < 4; i_++) { \
                const int k_ = j_ * 4 + i_; \
                se[k_] += __expf(xv[i_]); \
                xt[k_] = ((C) == tc_[k_]) ? xv[i_] : xt[k_]; \
            } \
        } \
    } while (0)

    // steady state: at iteration c, bufA holds class c, bufB holds class c+1.
    // consume FIRST, then reload the same buffer two classes ahead (WAR on
    // registers is free; the reload stays in flight across the next CONS).
    #pragma unroll 1
    for (int c = 0; c < NCLS - 1; c += 2) {
        CONS(bufA, c);
        if (c + 2 < NCLS) LOADQ(bufA, c + 2);
        CONS(bufB, c + 1);
        if (c + 3 < NCLS) LOADQ(bufB, c + 3);
    }
    CONS(bufA, NCLS - 1);   // class 18 (loaded at c=16)
#undef LOADQ
#undef CONS

    __syncthreads();   // bins zeroed at top

    // ---- epilogue: lp = xt - log(se), per-wave LDS bins, branch-free ----
    float* wb = &s_bins[wave * 4 * BSTRIDE];
    #pragma unroll
    for (int k = 0; k < 8; k++) {
        const float lp = xt[k] - __logf(se[k]);
        const int t = tc_[k];
        atomicAdd(&wb[0 * BSTRIDE + t], lp);
        atomicAdd(&wb[1 * BSTRIDE + t], 1.f);
        const int ta = ((gate >> k) & 1u) ? t : TRASH;
        atomicAdd(&wb[2 * BSTRIDE + ta], lp);
        atomicAdd(&wb[3 * BSTRIDE + ta], 1.f);
    }

    // ---- BCE block reduction ----
    bp = wave_reduce_add(bp);
    bn = wave_reduce_add(bn);
    pc = wave_reduce_add(pc);
    nc = wave_reduce_add(nc);
    if (lane == 0) { s_red[0][wave] = bp; s_red[1][wave] = bn;
                     s_red[2][wave] = pc; s_red[3][wave] = nc; }
    __syncthreads();

    if (tid < 4 * NCLS) {
        const int acc = tid / NCLS;
        const int c = tid - acc * NCLS;
        float s = 0.f;
        #pragma unroll
        for (int w = 0; w < 4; w++)
            s += s_bins[(w * 4 + acc) * BSTRIDE + c];
        atomicAdd(&g_bins[GBINS(acc, n, c)], s);
    } else if (tid < 4 * NCLS + 4) {
        const int k = tid - 4 * NCLS;
        atomicAdd(&g_sc[n * 4 + k],
                  s_red[k][0] + s_red[k][1] + s_red[k][2] + s_red[k][3]);
    }
}

// ---------------------------------------------------------------------------
// Finalize: weights from counts, weighted combines, 4 outputs. Reads 2.5 KB.
// ---------------------------------------------------------------------------
__global__ void final_kernel(const float* __restrict__ g_bins,
                             const float* __restrict__ g_sc,
                             float* __restrict__ out)
{
    __shared__ float s_seg[NIMG];
    __shared__ float s_att[NIMG];
    const int t = threadIdx.x;
    if (t < NIMG) {
        const int n = t;
        float tot = 0.f, tota = 0.f;
        for (int c = 0; c < NCLS; c++) {
            tot  += g_bins[GBINS(1, n, c)];
            tota += g_bins[GBINS(3, n, c)];
        }
        tot  = fmaxf(tot, 1.0f);
        tota = fmaxf(tota, 1.0f);
        float wp = 0.f, wplp = 0.f, wpa = 0.f, wplpa = 0.f;
        for (int c = 0; c < NCLS; c++) {
            const float cs = g_bins[GBINS(1, n, c)];
            const float ca = g_bins[GBINS(3, n, c)];
            const float w  = (cs > 0.f) ? (2.0f - cs / tot ) : 1.0f;
            const float wa = (ca > 0.f) ? (2.0f - ca / tota) : 1.0f;
            wp    += w * cs;    wplp  += w * g_bins[GBINS(0, n, c)];
            wpa   += wa * ca;   wplpa += wa * g_bins[GBINS(2, n, c)];
        }
        s_seg[n] = -wplp  / fmaxf(wp,  1e-12f);
        s_att[n] = -wplpa / fmaxf(wpa, 1e-12f);
    }
    __syncthreads();
    if (t == 0) {
        float seg = 0.f, att = 0.f, bpt = 0.f, bnt = 0.f, pct = 0.f, nct = 0.f;
        for (int n = 0; n < NIMG; n++) {
            seg += s_seg[n];
            att += s_att[n];
            bpt += g_sc[n * 4 + 0];
            bnt += g_sc[n * 4 + 1];
            pct += g_sc[n * 4 + 2];
            nct += g_sc[n * 4 + 3];
        }
        const float s = fmaxf(pct + nct, 1.0f);
        const float bce = (nct / s) * bpt + (pct / s) * bnt;
        out[0] = seg;
        out[1] = 20.0f * bce / (float)(NIMG * HW);
        out[2] = att;
        out[3] = 0.0f;
    }
}

extern "C" void kernel_launch(void* const* d_in, const int* in_sizes, int n_in,
                              void* d_out, int out_size, void* d_ws, size_t ws_size,
                              hipStream_t stream) {
    const float* segin    = (const float*)d_in[0];
    const float* edgein   = (const float*)d_in[1];
    const int*   segmask  = (const int*)d_in[2];
    const int*   edgemask = (const int*)d_in[3];
    float* out = (float*)d_out;

    float* g_bins = (float*)d_ws;                 // 4*8*19 = 608 floats
    float* g_sc   = g_bins + 4 * NIMG * NCLS;     // 8*4 = 32 floats

    hipMemsetAsync(d_ws, 0, (4 * NIMG * NCLS + 4 * NIMG) * sizeof(float), stream);

    main_kernel<<<dim3(TILES, NIMG), 256, 0, stream>>>(
        segin, edgein, segmask, edgemask, g_bins, g_sc);
    final_kernel<<<1, 64, 0, stream>>>(g_bins, g_sc, out);
}